// Round 9
// baseline (984.086 us; speedup 1.0000x reference)
//
#include <hip/hip_runtime.h>
#include <stdint.h>
#include <stddef.h>

#define AS1 __attribute__((address_space(1)))
#define AS3 __attribute__((address_space(3)))

typedef __attribute__((ext_vector_type(4))) float f32x4;
typedef __attribute__((ext_vector_type(8))) short bf16x8;
typedef __attribute__((ext_vector_type(2))) unsigned long long u64x2;

static __device__ __forceinline__ unsigned short f2b(float x) {
  union { float f; uint32_t u; } c; c.f = x;
  return (unsigned short)((c.u + 0x7FFFu + ((c.u >> 16) & 1u)) >> 16);
}
static __device__ __forceinline__ float fsig(float x) {
  return __builtin_amdgcn_rcpf(1.f + __expf(-x));
}
static __device__ __forceinline__ float ftanh(float x) {
  return 1.f - 2.f * __builtin_amdgcn_rcpf(__expf(2.f * x) + 1.f);
}

// ---------------- prep kernels ----------------

__global__ __launch_bounds__(256) void k_cvt_bf16(const float* __restrict__ s,
                                                  unsigned short* __restrict__ d,
                                                  int n4) {
  int i = blockIdx.x * 256 + threadIdx.x;
  int stride = gridDim.x * 256;
  for (; i < n4; i += stride) {
    float4 v = ((const float4*)s)[i];
    ushort4 o;
    o.x = f2b(v.x); o.y = f2b(v.y); o.z = f2b(v.z); o.w = f2b(v.w);
    ((ushort4*)d)[i] = o;
  }
}

// row-permuted f32->bf16: permuted row rp = w*64 + q*16 + j  <-  src row q*512 + w*16 + j
__global__ __launch_bounds__(128) void k_cvt_perm(const float* __restrict__ s,
                                                  unsigned short* __restrict__ d) {
  int rp = blockIdx.x;
  int w = rp >> 6, q = (rp >> 4) & 3, j = rp & 15;
  int rs = q * 512 + w * 16 + j;
  float4 v = ((const float4*)(s + (size_t)rs * 512))[threadIdx.x];
  ushort4 o;
  o.x = f2b(v.x); o.y = f2b(v.y); o.z = f2b(v.z); o.w = f2b(v.w);
  ((ushort4*)(d + (size_t)rp * 512))[threadIdx.x] = o;
}

__global__ __launch_bounds__(256) void k_bias_perm(const float* __restrict__ a,
                                                   const float* __restrict__ b,
                                                   float* __restrict__ o) {
  int rp = blockIdx.x * 256 + threadIdx.x;
  if (rp < 2048) {
    int w = rp >> 6, q = (rp >> 4) & 3, j = rp & 15;
    int rs = q * 512 + w * 16 + j;
    o[rp] = a[rs] + b[rs];
  }
}

// row m = t*16+b  <-  emb[xs[b][t]]  (bf16)
__global__ __launch_bounds__(128) void k_emb_gather(const int* __restrict__ xs,
                                                    const float* __restrict__ emb,
                                                    unsigned short* __restrict__ out) {
  int m = blockIdx.x;
  int tok = xs[(m & 15) * 128 + (m >> 4)];
  float4 v = ((const float4*)(emb + (size_t)tok * 512))[threadIdx.x];
  ushort4 o;
  o.x = f2b(v.x); o.y = f2b(v.y); o.z = f2b(v.z); o.w = f2b(v.w);
  ((ushort4*)(out + (size_t)m * 512))[threadIdx.x] = o;
}

// ---------------- bf16 GEMM, B^T layout (m97-style; used for gates) --------
__global__ __launch_bounds__(256) void k_gemm_bt(const unsigned short* __restrict__ A,
                                                 const unsigned short* __restrict__ Bt,
                                                 const float* __restrict__ bias,
                                                 float* __restrict__ C,
                                                 int M, int N, int K) {
  __shared__ unsigned short As[128 * 32];
  __shared__ unsigned short Bs[128 * 32];
  const int tiles_n = N >> 7;
  const int tm = blockIdx.x / tiles_n;
  const int tn = blockIdx.x % tiles_n;
  const int m0 = tm << 7, n0 = tn << 7;
  const int tid = threadIdx.x;
  const int wave = tid >> 6, lane = tid & 63;
  const int wr = wave >> 1, wc = wave & 1;
  f32x4 acc[4][4] = {};

  const int lo = wave * 2048 + lane * 16;
  for (int k0 = 0; k0 < K; k0 += 32) {
#pragma unroll
    for (int i = 0; i < 2; ++i) {
      int o = lo + i * 1024;
      int row = o >> 6, kb = o & 63;
      __builtin_amdgcn_global_load_lds(
          (const AS1 uint32_t*)((const char*)A + ((size_t)(m0 + row) * K + k0) * 2 + kb),
          (AS3 uint32_t*)((char*)As + wave * 2048 + i * 1024), 16, 0, 0);
    }
#pragma unroll
    for (int i = 0; i < 2; ++i) {
      int o = lo + i * 1024;
      int row = o >> 6, kb = o & 63;
      __builtin_amdgcn_global_load_lds(
          (const AS1 uint32_t*)((const char*)Bt + ((size_t)(n0 + row) * K + k0) * 2 + kb),
          (AS3 uint32_t*)((char*)Bs + wave * 2048 + i * 1024), 16, 0, 0);
    }
    __syncthreads();
    bf16x8 af[4], bfr[4];
    const int lrow = lane & 15;
    const int kb16 = (lane >> 4) * 16;
#pragma unroll
    for (int i = 0; i < 4; ++i)
      af[i] = *(const bf16x8*)((const char*)As + (wr * 64 + i * 16 + lrow) * 64 + kb16);
#pragma unroll
    for (int j = 0; j < 4; ++j)
      bfr[j] = *(const bf16x8*)((const char*)Bs + (wc * 64 + j * 16 + lrow) * 64 + kb16);
#pragma unroll
    for (int i = 0; i < 4; ++i)
#pragma unroll
      for (int j = 0; j < 4; ++j)
        acc[i][j] = __builtin_amdgcn_mfma_f32_16x16x32_bf16(af[i], bfr[j], acc[i][j], 0, 0, 0);
    __syncthreads();
  }
#pragma unroll
  for (int j = 0; j < 4; ++j) {
    int col = n0 + wc * 64 + j * 16 + (lane & 15);
    float bv = bias[col];
#pragma unroll
    for (int i = 0; i < 4; ++i) {
      int r0 = m0 + wr * 64 + i * 16 + (lane >> 4) * 4;
#pragma unroll
      for (int r = 0; r < 4; ++r)
        C[(size_t)(r0 + r) * N + col] = acc[i][j][r] + bv;
    }
  }
}

// ---------------- fused LSTM + output GEMM ----------------
// 248 WGs x 256 thr, ~452 regs/wave -> 1 WG/CU -> all co-resident by
// construction (no dispatch-order deadlock possible).
//  bid 0..7   : LSTM role — 4 independent waves/WG, each = r8's proven worker
//               (flagless sentinel consumer) + r7's producer flag
//               (h-stores -> vmcnt(0) -> flag), certifying the slot for GEMM.
//  bid 8..247 : persistent GEMM workers. Atomic-ticket tiles, m-ascending.
//               Per tile: poll the 32 flags of step t=m*8+7 (per-producer
//               sequential steps + drain-before-flag => all slots <= t+1
//               visible at the coherence point), then m97 K-loop where A is
//               staged via AGENT-scope loads (hs lives at the coherence
//               point; normal loads could hit a stale XCD L2) and B (static
//               weights) via global_load_lds.

__global__ __launch_bounds__(256, 1) void k_fused(
    const float* __restrict__ gp, const unsigned short* __restrict__ wp,
    const float* __restrict__ encc, unsigned short* __restrict__ hsb,
    uint32_t* __restrict__ flags, const unsigned short* __restrict__ woutb,
    const float* __restrict__ bout, float* __restrict__ out,
    uint32_t* __restrict__ ticket) {
  __shared__ unsigned short As[128 * 32];
  __shared__ unsigned short Bs[128 * 32];
  __shared__ int sh_tile;
  __shared__ int sh_rdy;

  const int bid = blockIdx.x;
  const int tid = threadIdx.x;

  if (bid < 8) {
    // ================= LSTM role (per-wave worker, no block sync) =========
    const int w = (bid << 2) | (tid >> 6);  // worker 0..31
    const int l = tid & 63;
    const int lr = l & 15;
    const int lk = l >> 4;
    const int col = w * 16 + lr;

    bf16x8 bfr[4][16];
#pragma unroll
    for (int j = 0; j < 4; ++j)
#pragma unroll
      for (int ks = 0; ks < 16; ++ks)
        bfr[j][ks] = *(const bf16x8*)((const char*)wp +
            (size_t)(w * 64 + j * 16 + lr) * 1024 + ks * 64 + lk * 16);

    float cst[4];
#pragma unroll
    for (int r = 0; r < 4; ++r) cst[r] = encc[(lk * 4 + r) * 512 + col];

    const uint64_t K1 = 0x0001000100010001ull;
    const uint64_t K8 = 0x8000800080008000ull;
    const int u64off = lr * 128 + lk * 2;

    float gnx[4][4];
#pragma unroll
    for (int j = 0; j < 4; ++j)
#pragma unroll
      for (int r = 0; r < 4; ++r)
        gnx[j][r] = gp[(size_t)(lk * 4 + r) * 2048 + w * 64 + j * 16 + lr];

    for (int t = 0; t < 128; ++t) {
      float gcur[4][4];
#pragma unroll
      for (int j = 0; j < 4; ++j)
#pragma unroll
        for (int r = 0; r < 4; ++r) gcur[j][r] = gnx[j][r];

      union AF { uint64_t q[2]; bf16x8 v; } af[16];
      const uint64_t* hb = (const uint64_t*)(hsb + (size_t)t * 8192);
      {
        int guard = 0;
        for (;;) {
#pragma unroll
          for (int ks = 0; ks < 16; ++ks) {
            af[ks].q[0] = __hip_atomic_load(hb + u64off + ks * 8, __ATOMIC_RELAXED,
                                            __HIP_MEMORY_SCOPE_AGENT);
            af[ks].q[1] = __hip_atomic_load(hb + u64off + ks * 8 + 1, __ATOMIC_RELAXED,
                                            __HIP_MEMORY_SCOPE_AGENT);
          }
          uint64_t bad = 0;
#pragma unroll
          for (int ks = 0; ks < 16; ++ks) {
            bad |= (~af[ks].q[0] - K1) & af[ks].q[0] & K8;
            bad |= (~af[ks].q[1] - K1) & af[ks].q[1] & K8;
          }
          if (__all(bad == 0)) break;
          __builtin_amdgcn_s_sleep(1);
          if (++guard > (1 << 20)) break;  // tripwire: wrong, not hung
        }
      }

      f32x4 acc[4] = {};
#pragma unroll
      for (int ks = 0; ks < 16; ++ks) {
#pragma unroll
        for (int j = 0; j < 4; ++j)
          acc[j] = __builtin_amdgcn_mfma_f32_16x16x32_bf16(af[ks].v, bfr[j][ks],
                                                           acc[j], 0, 0, 0);
      }

      uint32_t pk[4];
#pragma unroll
      for (int r = 0; r < 4; ++r) {
        float iv = fsig(acc[0][r] + gcur[0][r]);
        float fv = fsig(acc[1][r] + gcur[1][r]);
        float gv = ftanh(acc[2][r] + gcur[2][r]);
        float ov = fsig(acc[3][r] + gcur[3][r]);
        cst[r] = fv * cst[r] + iv * gv;
        float hv = ov * ftanh(cst[r]);
        uint32_t mine = f2b(hv);
        uint32_t other = (uint32_t)__shfl_xor((int)mine, 1);
        pk[r] = mine | (other << 16);
      }
      uint32_t* hout = (uint32_t*)(hsb + (size_t)(t + 1) * 8192);
      if ((lr & 1) == 0) {
#pragma unroll
        for (int r = 0; r < 4; ++r)
          __hip_atomic_store(hout + ((lk * 4 + r) * 512 + col) / 2, pk[r],
                             __ATOMIC_RELAXED, __HIP_MEMORY_SCOPE_AGENT);
      }
      // drain h-stores, then certify the slot for GEMM consumers
      asm volatile("s_waitcnt vmcnt(0)" ::: "memory");
      if (l == 0)
        __hip_atomic_store(flags + (size_t)t * 32 + w, 1u,
                           __ATOMIC_RELAXED, __HIP_MEMORY_SCOPE_AGENT);

      if (t < 127) {
#pragma unroll
        for (int j = 0; j < 4; ++j)
#pragma unroll
          for (int r = 0; r < 4; ++r)
            gnx[j][r] = gp[(size_t)((t + 1) * 16 + lk * 4 + r) * 2048 +
                           w * 64 + j * 16 + lr];
      }
    }
  } else {
    // ================= persistent GEMM role =================
    const unsigned short* Ab = hsb + 16 * 512;  // [2048][512] bf16 (slots 1..128)
    const int wave = tid >> 6, lane = tid & 63;
    const int wr = wave >> 1, wc = wave & 1;
    const int lo = wave * 2048 + lane * 16;

    for (;;) {
      if (tid == 0) sh_tile = (int)atomicAdd(ticket, 1u);
      __syncthreads();
      const int tile = sh_tile;
      __syncthreads();
      if (tile >= 4000) break;
      const int m = tile / 250, n = tile % 250;
      const int m0 = m << 7, n0 = n << 7;

      // ---- wait for rows m0..m0+127 (flags of step t = m*8+7) ----
      if (tid == 0) sh_rdy = 0;
      __syncthreads();
      {
        const uint32_t* fp = flags + (size_t)(m * 8 + 7) * 32;
        int guard = 0;
        for (;;) {
          if (tid < 64) {
            uint32_t fl = __hip_atomic_load(fp + (tid & 31), __ATOMIC_RELAXED,
                                            __HIP_MEMORY_SCOPE_AGENT);
            if (__all(fl != 0u) && tid == 0) sh_rdy = 1;
          }
          __syncthreads();
          if (sh_rdy) break;
          if (++guard > (1 << 15)) break;  // tripwire: wrong, not hung
          __builtin_amdgcn_s_sleep(32);   // keep poll traffic off the LSTM path
          __builtin_amdgcn_s_sleep(32);
          __syncthreads();
        }
      }

      // ---- m97 K-loop; A staged via agent loads, B via global_load_lds ----
      f32x4 acc[4][4] = {};
      for (int k0 = 0; k0 < 512; k0 += 32) {
#pragma unroll
        for (int i = 0; i < 2; ++i) {
          int o = lo + i * 1024;
          int row = o >> 6, kb = o & 63;
          const uint64_t* ap = (const uint64_t*)((const char*)Ab +
              ((size_t)(m0 + row) * 512 + k0) * 2 + kb);
          uint64_t u0 = __hip_atomic_load(ap, __ATOMIC_RELAXED,
                                          __HIP_MEMORY_SCOPE_AGENT);
          uint64_t u1 = __hip_atomic_load(ap + 1, __ATOMIC_RELAXED,
                                          __HIP_MEMORY_SCOPE_AGENT);
          u64x2 av; av.x = u0; av.y = u1;
          *(u64x2*)((char*)As + o) = av;
          __builtin_amdgcn_global_load_lds(
              (const AS1 uint32_t*)((const char*)woutb +
                  ((size_t)(n0 + row) * 512 + k0) * 2 + kb),
              (AS3 uint32_t*)((char*)Bs + o), 16, 0, 0);
        }
        __syncthreads();
        bf16x8 af[4], bfr[4];
        const int lrow = lane & 15;
        const int kb16 = (lane >> 4) * 16;
#pragma unroll
        for (int i = 0; i < 4; ++i)
          af[i] = *(const bf16x8*)((const char*)As + (wr * 64 + i * 16 + lrow) * 64 + kb16);
#pragma unroll
        for (int j = 0; j < 4; ++j)
          bfr[j] = *(const bf16x8*)((const char*)Bs + (wc * 64 + j * 16 + lrow) * 64 + kb16);
#pragma unroll
        for (int i = 0; i < 4; ++i)
#pragma unroll
          for (int j = 0; j < 4; ++j)
            acc[i][j] = __builtin_amdgcn_mfma_f32_16x16x32_bf16(af[i], bfr[j],
                                                                acc[i][j], 0, 0, 0);
        __syncthreads();
      }
#pragma unroll
      for (int j = 0; j < 4; ++j) {
        int col = n0 + wc * 64 + j * 16 + (lane & 15);
        float bv = bout[col];
#pragma unroll
        for (int i = 0; i < 4; ++i) {
          int r0 = m0 + wr * 64 + i * 16 + (lane >> 4) * 4;
#pragma unroll
          for (int r = 0; r < 4; ++r)
            out[(size_t)(r0 + r) * 32000 + col] = acc[i][j][r] + bv;
        }
      }
    }
  }
}

// ---------------- launch ----------------

extern "C" void kernel_launch(void* const* d_in, const int* in_sizes, int n_in,
                              void* d_out, int out_size, void* d_ws, size_t ws_size,
                              hipStream_t stream) {
  (void)in_sizes; (void)n_in; (void)out_size; (void)ws_size;
  const int* xs = (const int*)d_in[0];
  const float* ench = (const float*)d_in[2];
  const float* encc = (const float*)d_in[3];
  const float* emb  = (const float*)d_in[4];
  const float* Wih  = (const float*)d_in[5];
  const float* Whh  = (const float*)d_in[6];
  const float* bih  = (const float*)d_in[7];
  const float* bhh  = (const float*)d_in[8];
  const float* Wout = (const float*)d_in[9];
  const float* bout = (const float*)d_in[10];
  float* out = (float*)d_out;

  char* ws = (char*)d_ws;
  size_t off = 0;
  auto take = [&](size_t bytes) {
    char* p = ws + off;
    off += (bytes + 255) & ~(size_t)255;
    return p;
  };
  float* gates_pre      = (float*)take(2048ull * 2048 * 4);        // [T*B][4H] permuted cols
  unsigned short* hsb   = (unsigned short*)take(129ull * 16 * 512 * 2);  // h states bf16
  unsigned short* aemb  = (unsigned short*)take(2048ull * 512 * 2);
  unsigned short* wih_b = (unsigned short*)take(2048ull * 512 * 2);      // permuted rows
  unsigned short* wp_b  = (unsigned short*)take(2048ull * 512 * 2);      // permuted W_hh
  unsigned short* wout_b= (unsigned short*)take(32000ull * 512 * 2);
  float* bias1          = (float*)take(2048 * 4);                        // permuted
  uint32_t* flags       = (uint32_t*)take(128ull * 32 * 4);              // step flags
  uint32_t* ticket      = (uint32_t*)take(256);                          // GEMM tickets

  k_cvt_perm<<<2048, 128, 0, stream>>>(Wih, wih_b);
  k_cvt_perm<<<2048, 128, 0, stream>>>(Whh, wp_b);
  k_cvt_bf16<<<2048, 256, 0, stream>>>(Wout, wout_b, 32000 * 512 / 4);
  k_emb_gather<<<2048, 128, 0, stream>>>(xs, emb, aemb);
  k_bias_perm<<<8, 256, 0, stream>>>(bih, bhh, bias1);

  // slot 0 = enc_h (bf16); slots 1..128 = 0xFFFF sentinel
  k_cvt_bf16<<<2, 256, 0, stream>>>(ench, hsb, 16 * 512 / 4);
  hipMemsetAsync(hsb + 16 * 512, 0xFF, 128ull * 16 * 512 * 2, stream);
  hipMemsetAsync(flags, 0, 128ull * 32 * 4, stream);
  hipMemsetAsync(ticket, 0, 256, stream);

  // gates_pre = aemb @ W_ih_perm^T + (b_ih + b_hh)_perm
  k_gemm_bt<<<256, 256, 0, stream>>>(aemb, wih_b, bias1, gates_pre, 2048, 2048, 512);

  // fused LSTM (8 WGs) + flag-gated persistent output GEMM (240 WGs)
  k_fused<<<248, 256, 0, stream>>>(gates_pre, wp_b, encc, hsb, flags,
                                   wout_b, bout, out, ticket);
}